// Round 11
// baseline (310.497 us; speedup 1.0000x reference)
//
#include <hip/hip_runtime.h>
#include <hip/hip_bf16.h>
#include <math.h>

// MLA forward, bf16 MFMA pipeline v18.
//  v18 = v17 with counted-vmcnt 3-buffer GEMM pipeline (T4):
//   - gemm_bf16 / pv_gemm: 2 stages in flight; per K-step {STAGE(s+2) -> compute
//     buf[s%3] -> s_waitcnt vmcnt(LOADS) -> raw s_barrier}. Never drains vmcnt to
//     0 in steady state (the old __syncthreads waited for the just-issued prefetch
//     every step - the m97/T4 stall). LOADS = BM/64+BN/64 per thread, constexpr.
//   - pv_gemm: end-of-phase barrier protects LDS reuse across its 2 phases.
//   - wo_permute + sum_cast2 merged into one dispatch (epilogue_prep).
//  Kept: v13 row_stats_p (empirical optimum; 3 structural attempts lost), merged
//  kv up-proj (MERGEKV), zrow-in-cast_all, rope_qk, pair-balanced 2-chunk pv_gemm,
//  XOR LDS swizzle, split-K krt, 64x64 down-proj, triangle-packed P^T, overlays.

namespace {

constexpr int T   = 2048;
constexpr int D   = 2048;
constexpr int NH  = 16;
constexpr int DH  = 128;
constexpr int DRH = 64;
constexpr int DC  = 512;
constexpr int QK  = 192;
constexpr float SCL2E = 0.07216878364870322f * 1.4426950408889634f; // (1/sqrt(192))*log2(e)

// triangle-packed P^T per head: tile j (l in [64j,64j+64)) has row length Lj=2048-64j,
// tile offset OJ(j) = 2048*j*(65-j); per-head size PH = OJ(32).
constexpr long long PH = 2048LL * 32 * 33;  // 2,162,688 shorts

typedef __attribute__((ext_vector_type(8))) short short8;
typedef __attribute__((ext_vector_type(4))) float f32x4;

#define MFMA16(a, b, c) __builtin_amdgcn_mfma_f32_16x16x32_bf16((a), (b), (c), 0, 0, 0)

__device__ __forceinline__ unsigned short f2b(float x) {   // round-to-nearest-even
    unsigned u = __float_as_uint(x);
    unsigned r = (u + 0x7FFFu + ((u >> 16) & 1u)) >> 16;
    return (unsigned short)r;
}
__device__ __forceinline__ unsigned short f2bt(float x) {  // truncate (1 VALU op)
    return (unsigned short)(__float_as_uint(x) >> 16);
}
__device__ __forceinline__ float b2f(unsigned short s) {
    return __uint_as_float(((unsigned)s) << 16);
}

typedef __attribute__((address_space(1))) const unsigned int* gas_t;
typedef __attribute__((address_space(3))) unsigned int* las_t;
__device__ __forceinline__ void async16(const unsigned short* g, unsigned short* l) {
    __builtin_amdgcn_global_load_lds((gas_t)(const void*)g, (las_t)(void*)l, 16, 0, 0);
}

template<int N>
__device__ __forceinline__ void vmwait() {
    if constexpr (N == 0)      asm volatile("s_waitcnt vmcnt(0)" ::: "memory");
    else if constexpr (N == 2) asm volatile("s_waitcnt vmcnt(2)" ::: "memory");
    else if constexpr (N == 3) asm volatile("s_waitcnt vmcnt(3)" ::: "memory");
    else static_assert(N == 0 || N == 2 || N == 3, "add vmcnt case");
}

// ---------------- fused fp32 -> bf16 cast/repack of h + 7 weight tensors ----------------
constexpr long long SZ_H    = (long long)T * D;
constexpr long long SZ_DKV  = (long long)DC * D;
constexpr long long SZ_UK   = (long long)DH * NH * DC;
constexpr long long SZ_UV   = SZ_UK;
constexpr long long SZ_DQ   = SZ_DKV;
constexpr long long SZ_UQ   = SZ_UK;
constexpr long long SZ_QR   = (long long)DRH * NH * DC;
constexpr long long SZ_KR   = (long long)DRH * D;
constexpr long long C0 = SZ_H;
constexpr long long C1 = C0 + SZ_DKV;
constexpr long long C2 = C1 + SZ_UK;
constexpr long long C3 = C2 + SZ_UV;
constexpr long long C4 = C3 + SZ_DQ;
constexpr long long C5 = C4 + SZ_UQ;
constexpr long long C6 = C5 + SZ_QR;
constexpr long long C7 = C6 + SZ_KR;   // 10485760
constexpr long long C8 = C7 + 32768;   // + zrow (NH*T floats) zero-fill

__global__ __launch_bounds__(256) void cast_all(
    const float* __restrict__ h,   const float* __restrict__ wdkv,
    const float* __restrict__ wuk, const float* __restrict__ wuv,
    const float* __restrict__ wdq, const float* __restrict__ wuq,
    const float* __restrict__ wqr, const float* __restrict__ wkr,
    unsigned short* __restrict__ hb,   unsigned short* __restrict__ dkvb,
    unsigned short* __restrict__ dqb,  unsigned short* __restrict__ ukvb,
    unsigned short* __restrict__ wqall, unsigned short* __restrict__ krb,
    float* __restrict__ zrow)
{
    long long i4 = ((long long)blockIdx.x * 256 + threadIdx.x) * 4;
    const float* src; unsigned short* dst; long long soff, doff;
    if      (i4 < C0) { src = h;    dst = hb;   soff = i4;      doff = soff; }
    else if (i4 < C1) { src = wdkv; dst = dkvb; soff = i4 - C0; doff = soff; }
    else if (i4 < C2) { // wuk [128][16][512] -> ukvb[n][256][512] rows 0:128
        src = wuk; dst = ukvb; soff = i4 - C1;
        long long e = soff >> 13, n = (soff >> 9) & 15, c = soff & 511;
        doff = n * 131072 + e * 512 + c;
    }
    else if (i4 < C3) { // wuv [128][16][512] -> ukvb[n][256][512] rows 128:256
        src = wuv; dst = ukvb; soff = i4 - C2;
        long long e = soff >> 13, n = (soff >> 9) & 15, c = soff & 511;
        doff = n * 131072 + (128 + e) * 512 + c;
    }
    else if (i4 < C4) { src = wdq;  dst = dqb;  soff = i4 - C3; doff = soff; }
    else if (i4 < C5) { // wuq [128][16][512] -> wqall[n][192][512] rows 0:128
        src = wuq; dst = wqall; soff = i4 - C4;
        long long e = soff >> 13, n = (soff >> 9) & 15, c = soff & 511;
        doff = n * 98304 + e * 512 + c;
    }
    else if (i4 < C6) { // wqr [64][16][512] -> wqall[n][192][512] rows 128:192
        src = wqr; dst = wqall; soff = i4 - C5;
        long long e = soff >> 13, n = (soff >> 9) & 15, c = soff & 511;
        doff = n * 98304 + (128 + e) * 512 + c;
    }
    else if (i4 < C7) { src = wkr;  dst = krb;  soff = i4 - C6; doff = soff; }
    else {             // zero zrow (replaces hipMemsetAsync)
        float4 z4; z4.x = 0.f; z4.y = 0.f; z4.z = 0.f; z4.w = 0.f;
        *(float4*)(zrow + (i4 - C7)) = z4;
        return;
    }
    float4 v = *(const float4*)(src + soff);
    uint2 pk;
    pk.x = (unsigned)f2b(v.x) | ((unsigned)f2b(v.y) << 16);
    pk.y = (unsigned)f2b(v.z) | ((unsigned)f2b(v.w) << 16);
    *(uint2*)(dst + doff) = pk;
}

// ---------------- bf16 MFMA NT GEMM, counted-vmcnt 3-buffer pipeline -------
// LDS slot swizzle: slot holds global k-chunk (slot ^ (row>>1)&3); reader fetches
// slot q^((row>>1)&3) -> bank-conflict-free (measured 0).
// Pipeline: 2 stages in flight; steady-state wait = vmcnt(LOADS), never 0 (T4).
// SPLITK: blockIdx.z slices K. MERGEKV: blockIdx.y==1 routes C to C2/ldc2/sC2.
template<int BM, int BN, int WM, int WN, bool OUTB, bool SPLITK = false, bool MERGEKV = false>
__global__ __launch_bounds__(256) void gemm_bf16(
    const unsigned short* __restrict__ A, const unsigned short* __restrict__ B,
    void* __restrict__ C, int K, int lda, int ldb, int ldc,
    long long sB, long long sC,
    void* __restrict__ C2, int ldc2, long long sC2)
{
    constexpr int MT = WM / 16, NT = WN / 16;
    constexpr int WX = BN / WN;
    constexpr int LOADS = BM / 64 + BN / 64;   // per-thread global_load_lds per stage
    __shared__ unsigned short As[3][BM * 32];
    __shared__ unsigned short Bs[3][BN * 32];
    const int tid = (int)threadIdx.x;
    const int wave = tid >> 6, lane = tid & 63;
    const int q = lane >> 4, c = lane & 15;
    const int wm = (wave / WX) * WM, wn = (wave % WX) * WN;
    const int m0 = (int)blockIdx.x * BM, n0 = (int)blockIdx.y * BN;

    const unsigned short* Ab;
    const unsigned short* Bb;
    long long cb;
    void* Cp = C;
    int ldcl = ldc;
    int n0c = n0;
    if constexpr (SPLITK) {
        int koff = (int)blockIdx.z * K;
        Ab = A + koff;
        Bb = B + koff;
        cb = (long long)blockIdx.z * sC;
    } else {
        Ab = A;
        Bb = B + (long long)blockIdx.z * sB;
        cb = (long long)blockIdx.z * sC;
    }
    if constexpr (MERGEKV) {
        if (blockIdx.y == 1) {
            Cp = C2; ldcl = ldc2; n0c = 0;
            cb = (long long)blockIdx.z * sC2;
        }
    }

    f32x4 acc[MT][NT];
#pragma unroll
    for (int i = 0; i < MT; ++i)
#pragma unroll
        for (int j = 0; j < NT; ++j) acc[i][j] = (f32x4){0.f, 0.f, 0.f, 0.f};

    auto STAGE = [&](int buf, int k0) {
#pragma unroll
        for (int i = 0; i < BM / 64; ++i) {
            int ch = tid + i * 256;
            async16(&Ab[(long long)(m0 + (ch >> 2)) * lda + k0 + (((ch & 3) ^ ((ch >> 3) & 3)) * 8)],
                    &As[buf][(i * 256 + wave * 64) * 8]);
        }
#pragma unroll
        for (int i = 0; i < BN / 64; ++i) {
            int ch = tid + i * 256;
            async16(&Bb[(long long)(n0 + (ch >> 2)) * ldb + k0 + (((ch & 3) ^ ((ch >> 3) & 3)) * 8)],
                    &Bs[buf][(i * 256 + wave * 64) * 8]);
        }
    };

    const int nsteps = K >> 5;
    STAGE(0, 0);
    if (nsteps > 1) { STAGE(1, 32); vmwait<LOADS>(); }
    else vmwait<0>();
    __builtin_amdgcn_s_barrier();
    for (int s = 0; s < nsteps; ++s) {
        int cur = s % 3;
        if (s + 2 < nsteps) STAGE((s + 2) % 3, (s + 2) * 32);
        short8 af[MT], bfr[NT];
#pragma unroll
        for (int i = 0; i < MT; ++i) {
            int row = wm + i * 16 + c;
            af[i] = *(const short8*)&As[cur][row * 32 + (q ^ ((row >> 1) & 3)) * 8];
        }
#pragma unroll
        for (int j = 0; j < NT; ++j) {
            int row = wn + j * 16 + c;
            bfr[j] = *(const short8*)&Bs[cur][row * 32 + (q ^ ((row >> 1) & 3)) * 8];
        }
#pragma unroll
        for (int i = 0; i < MT; ++i)
#pragma unroll
            for (int j = 0; j < NT; ++j)
                acc[i][j] = MFMA16(af[i], bfr[j], acc[i][j]);
        if (s + 1 < nsteps) {
            if (s + 2 < nsteps) vmwait<LOADS>();   // stage s+1 landed; s+2 in flight
            else vmwait<0>();                      // tail: drain the last stage
            __builtin_amdgcn_s_barrier();
        }
    }
#pragma unroll
    for (int i = 0; i < MT; ++i)
#pragma unroll
        for (int j = 0; j < NT; ++j) {
            int rbase = m0 + wm + i * 16 + q * 4;
            int col = n0c + wn + j * 16 + c;
#pragma unroll
            for (int rr = 0; rr < 4; ++rr) {
                long long off = cb + (long long)(rbase + rr) * ldcl + col;
                if (OUTB) ((unsigned short*)Cp)[off] = f2b(acc[i][j][rr]);
                else      ((float*)Cp)[off] = acc[i][j][rr];
            }
        }
}

// ---------------- RoPE (merged q + k) ----------------
__global__ __launch_bounds__(256) void rope_qk(unsigned short* __restrict__ qh,
                                               const float* __restrict__ krtp,
                                               unsigned short* __restrict__ kh,
                                               const float* __restrict__ fr)
{
    int idx = (int)blockIdx.x * 256 + (int)threadIdx.x;
    if (idx < NH * T * 32) {               // ---- rope_q ----
        int j = idx & 31;
        int t = (idx >> 5) & (T - 1);
        int n = idx >> 16;
        float sn, cs;
        sincosf(fr[t * 32 + j], &sn, &cs);
        long long base = ((long long)(n * T + t)) * QK + 128 + j;
        float x0 = b2f(qh[base]);
        float x1 = b2f(qh[base + 32]);
        qh[base]      = f2b(x0 * cs - x1 * sn);
        qh[base + 32] = f2b(x0 * sn + x1 * cs);
    } else {                               // ---- rope_k ----
        idx -= NH * T * 32;
        int j = idx & 31;
        int t = idx >> 5;
        float sn, cs;
        sincosf(fr[t * 32 + j], &sn, &cs);
        float x0 = 0.f, x1 = 0.f;
#pragma unroll
        for (int pth = 0; pth < 4; ++pth) {
            x0 += krtp[pth * (T * 64) + t * 64 + j];
            x1 += krtp[pth * (T * 64) + t * 64 + 32 + j];
        }
        unsigned short y0 = f2b((x0 * cs - x1 * sn) * (1.0f / 16.0f));
        unsigned short y1 = f2b((x0 * sn + x1 * cs) * (1.0f / 16.0f));
#pragma unroll
        for (int n = 0; n < NH; ++n) {
            long long base = ((long long)(n * T + t)) * QK + 128 + j;
            kh[base]      = y0;
            kh[base + 32] = y1;
        }
    }
}

// vbh[n][t][e] -> vt[n][e][t] scaled by 1/z_t
__global__ __launch_bounds__(256) void vtrans(const unsigned short* __restrict__ vbh,
                                              const float* __restrict__ zrow,
                                              unsigned short* __restrict__ vt)
{
    __shared__ unsigned short ts[32][33];
    __shared__ float zi[32];
    int t0 = (int)blockIdx.x * 32, e0 = (int)blockIdx.y * 32, n = (int)blockIdx.z;
    int tid = (int)threadIdx.x;
    if (tid < 32) zi[tid] = 1.0f / zrow[n * T + t0 + tid];
    int r = tid >> 3, cq = (tid & 7) * 4;
    const unsigned short* src = vbh + ((long long)(n * T + t0 + r)) * DH + e0 + cq;
#pragma unroll
    for (int i = 0; i < 4; ++i) ts[r][cq + i] = src[i];
    __syncthreads();
    unsigned short* dst = vt + ((long long)(n * DH + e0 + r)) * T + t0 + cq;
#pragma unroll
    for (int i = 0; i < 4; ++i) dst[i] = f2b(b2f(ts[cq + i][r]) * zi[cq + i]);
}

// ---------------- Pass A: z_t AND P^T store (single QK^T) ----------------
// v10/v13 implementation (empirical local optimum: 45.4us, VGPR 92). Operand-
// swapped MFMA: D row = l (A = K rows), D col = t (B = Q rows). P^T =
// bf16_trunc(exp2(s*scl)) stored triangle-packed per head; z via atomics.
// 1D grid 2048, XCD-swizzled, longest-first (tbi=31 first), 4 l-chunks.
__global__ __launch_bounds__(256) void row_stats_p(const unsigned short* __restrict__ qh,
                                                   const unsigned short* __restrict__ kh,
                                                   float* __restrict__ zrow,
                                                   unsigned short* __restrict__ Pbuf)
{
    int id = (int)blockIdx.x;
    int n = (id & 7) * 2 + ((id >> 3) & 1);
    int rest = id >> 4;                      // 0..127
    int tbi = 31 - (rest & 31);              // longest (tbi=31) first
    int chunk = rest >> 5;                   // 0..3
    int tid = (int)threadIdx.x, wave = tid >> 6, lane = tid & 63;
    int q = lane >> 4, c = lane & 15;
    int tw = tbi * 64 + wave * 16;

    __shared__ unsigned short Ks[64 * 200];

    // Q fragments for the wave's 16 t-rows (B operand)
    const unsigned short* qp = qh + ((long long)(n * T + tw + c)) * QK;
    short8 qf[6];
#pragma unroll
    for (int f = 0; f < 6; ++f) qf[f] = *(const short8*)(qp + f * 32 + q * 8);

    float z = 0.f;                           // z partial for t = tw + c
    const unsigned short* kbase = kh + (long long)n * T * QK;
    unsigned short* Ph = Pbuf + (long long)n * PH;

    short8 kreg[6];
    int lt = chunk;
    if (lt <= tbi) {
        const unsigned short* kp = kbase + (long long)lt * 64 * QK;
#pragma unroll
        for (int i = 0; i < 6; ++i) {
            int ch = tid + i * 256;
            int r = ch / 24, cc = ch - r * 24;
            kreg[i] = *(const short8*)(kp + r * QK + cc * 8);
        }
    }
    for (; lt <= tbi; lt += 4) {
        __syncthreads();
#pragma unroll
        for (int i = 0; i < 6; ++i) {
            int ch = tid + i * 256;
            int r = ch / 24, cc = ch - r * 24;
            *(short8*)&Ks[r * 200 + cc * 8] = kreg[i];
        }
        __syncthreads();
        if (lt + 4 <= tbi) {
            const unsigned short* kp = kbase + (long long)(lt + 4) * 64 * QK;
#pragma unroll
            for (int i = 0; i < 6; ++i) {
                int ch = tid + i * 256;
                int r = ch / 24, cc = ch - r * 24;
                kreg[i] = *(const short8*)(kp + r * QK + cc * 8);
            }
        }
        f32x4 d[4];
#pragma unroll
        for (int ls = 0; ls < 4; ++ls) d[ls] = (f32x4){0.f, 0.f, 0.f, 0.f};
        __builtin_amdgcn_s_setprio(1);
#pragma unroll
        for (int f = 0; f < 6; ++f)
#pragma unroll
            for (int ls = 0; ls < 4; ++ls) {
                short8 ka = *(const short8*)&Ks[(ls * 16 + c) * 200 + f * 32 + q * 8];
                d[ls] = MFMA16(ka, qf[f], d[ls]);
            }
        __builtin_amdgcn_s_setprio(0);
        // P^T tile base: tile lt, row (l-64lt) = ls*16+q*4+r, col (t-64lt)
        int L = T - lt * 64;                 // packed row length for tile lt
        unsigned short* pb = Ph + (long long)2048 * lt * (65 - lt)
                             + (long long)(q * 4) * L + (tbi - lt) * 64 + wave * 16 + c;
        if (lt == tbi) {                     // diagonal tile: mask l > t, store zeros
            int tl = wave * 16 + c;
#pragma unroll
            for (int ls = 0; ls < 4; ++ls)
#pragma unroll
                for (int r = 0; r < 4; ++r) {
                    float pe = exp2f(d[ls][r] * SCL2E);
                    bool ok = (ls * 16 + q * 4 + r) <= tl;
                    z += ok ? pe : 0.f;
                    pb[(ls * 16 + r) * L] = ok ? f2bt(pe) : (unsigned short)0;
                }
        } else {
#pragma unroll
            for (int ls = 0; ls < 4; ++ls)
#pragma unroll
                for (int r = 0; r < 4; ++r) {
                    float pe = exp2f(d[ls][r] * SCL2E);
                    z += pe;
                    pb[(ls * 16 + r) * L] = f2bt(pe);
                }
        }
    }
    // reduce z over the q dimension (lanes c, c+16, c+32, c+48 share t = tw+c)
    z += __shfl_xor(z, 16);
    z += __shfl_xor(z, 32);
    if (q == 0) atomicAdd(&zrow[n * T + tw + c], z);
}

// ---------------- Pass B: out[l][n*128+e] = sum_t P^T[l][t] * V'[e][t] ----------------
// NT GEMM on triangle-packed P^T (A) and vt (B), counted-vmcnt 3-buffer pipeline,
// pair-balanced: block = (head, pair pr, chunk of 2) -> l-tiles {pr, 31-pr},
// 33 t-tiles per pair. 2 chunks -> 2 bf16 partials. 512 uniform blocks = 2/CU.
__global__ __launch_bounds__(256) void pv_gemm(const unsigned short* __restrict__ Pbuf,
                                               const unsigned short* __restrict__ vt,
                                               unsigned short* __restrict__ p0,
                                               unsigned short* __restrict__ p1)
{
    __shared__ unsigned short As[3][64 * 32];
    __shared__ unsigned short Bs[3][128 * 32];
    int id = (int)blockIdx.x;
    int n = (id & 7) * 2 + ((id >> 3) & 1);
    int rest = id >> 4;                      // 0..31
    int pr = rest & 15;                      // pair index 0..15
    int chunk = (rest >> 4) & 1;             // 0..1
    const int tid = (int)threadIdx.x, wave = tid >> 6, lane = tid & 63;
    const int q = lane >> 4, c = lane & 15;
    const int wm = (wave >> 1) * 32, wn = (wave & 1) * 64;
    unsigned short* op = chunk ? p1 : p0;

#pragma unroll
    for (int ph = 0; ph < 2; ++ph) {
        int j = ph ? (31 - pr) : pr;
        int m0 = j * 64;
        int L = T - m0;                      // packed lda and K extent
        int ntile = 32 - j;
        const unsigned short* A = Pbuf + (long long)n * PH + (long long)2048 * j * (65 - j);
        const unsigned short* B = vt + (long long)n * DH * T + m0;

        f32x4 acc[2][4];
#pragma unroll
        for (int i = 0; i < 2; ++i)
#pragma unroll
            for (int jj = 0; jj < 4; ++jj) acc[i][jj] = (f32x4){0.f, 0.f, 0.f, 0.f};

        int tcnt = (chunk < ntile) ? (((ntile - 1 - chunk) >> 1) + 1) : 0;
        int nsteps = tcnt * 2;

        auto STAGE = [&](int buf, int k0) {
            async16(&A[(long long)(tid >> 2) * L + k0 + (((tid & 3) ^ ((tid >> 3) & 3)) * 8)],
                    &As[buf][wave * 512]);
#pragma unroll
            for (int i = 0; i < 2; ++i) {
                int ch = tid + i * 256;
                async16(&B[(long long)(ch >> 2) * T + k0 + (((ch & 3) ^ ((ch >> 3) & 3)) * 8)],
                        &Bs[buf][(i * 256 + wave * 64) * 8]);
            }
        };
        auto K0 = [&](int s) { return (chunk + ((s >> 1) << 1)) * 64 + (s & 1) * 32; };

        if (nsteps > 0) {
            STAGE(0, K0(0));
            if (nsteps > 1) { STAGE(1, K0(1)); vmwait<3>(); }
            else vmwait<0>();
        }
        __builtin_amdgcn_s_barrier();
        for (int s = 0; s < nsteps; ++s) {
            int cur = s % 3;
            if (s + 2 < nsteps) STAGE((s + 2) % 3, K0(s + 2));
            short8 af[2], bfr[4];
#pragma unroll
            for (int i = 0; i < 2; ++i) {
                int row = wm + i * 16 + c;
                af[i] = *(const short8*)&As[cur][row * 32 + (q ^ ((row >> 1) & 3)) * 8];
            }
#pragma unroll
            for (int jj = 0; jj < 4; ++jj) {
                int row = wn + jj * 16 + c;
                bfr[jj] = *(const short8*)&Bs[cur][row * 32 + (q ^ ((row >> 1) & 3)) * 8];
            }
#pragma unroll
            for (int i = 0; i < 2; ++i)
#pragma unroll
                for (int jj = 0; jj < 4; ++jj)
                    acc[i][jj] = MFMA16(af[i], bfr[jj], acc[i][jj]);
            if (s + 1 < nsteps) {
                if (s + 2 < nsteps) vmwait<3>();
                else vmwait<0>();
                __builtin_amdgcn_s_barrier();
            }
        }
        // always write (zeros when this chunk has no tiles) — partials are summed
#pragma unroll
        for (int i = 0; i < 2; ++i)
#pragma unroll
            for (int jj = 0; jj < 4; ++jj) {
                int rbase = m0 + wm + i * 16 + q * 4;
                int col = n * 128 + wn + jj * 16 + c;
#pragma unroll
                for (int rr = 0; rr < 4; ++rr)
                    op[(long long)(rbase + rr) * D + col] = f2b(acc[i][jj][rr]);
            }
        __builtin_amdgcn_s_barrier();   // LDS reuse across phases
    }
}

// Merged epilogue prep: blocks [0,D) -> wo_permute; blocks [D, D + T*D/2048) -> sum_cast2.
// wob[d][n*128 + e] = bf16(wo[d][e*16 + n]); attn2 = bf16(p0 + p1) (o may alias a).
__global__ __launch_bounds__(256) void epilogue_prep(const float* __restrict__ wo,
                                                     unsigned short* __restrict__ wob,
                                                     const unsigned short* a,
                                                     const unsigned short* b,
                                                     unsigned short* o)
{
    __shared__ float row[2048];
    int bid = (int)blockIdx.x;
    if (bid < D) {                         // ---- wo_permute ----
        const float* src = wo + (long long)bid * 2048;
#pragma unroll
        for (int i = 0; i < 8; ++i) row[threadIdx.x + i * 256] = src[threadIdx.x + i * 256];
        __syncthreads();
        unsigned short* dst = wob + (long long)bid * 2048;
#pragma unroll
        for (int i = 0; i < 8; ++i) {
            int j = threadIdx.x + i * 256;
            int n = j >> 7, e = j & 127;
            dst[j] = f2b(row[e * 16 + n]);
        }
    } else {                               // ---- sum_cast2 ----
        long long i = ((long long)(bid - D) * 256 + threadIdx.x) * 8;
        short8 va = *(const short8*)(a + i);
        short8 vb = *(const short8*)(b + i);
        short8 vo;
#pragma unroll
        for (int j = 0; j < 8; ++j)
            vo[j] = (short)f2b(b2f((unsigned short)va[j]) + b2f((unsigned short)vb[j]));
        *(short8*)(o + i) = vo;
    }
}

} // namespace

extern "C" void kernel_launch(void* const* d_in, const int* in_sizes, int n_in,
                              void* d_out, int out_size, void* d_ws, size_t ws_size,
                              hipStream_t stream)
{
    (void)in_sizes; (void)n_in; (void)out_size; (void)ws_size;
    const float* h    = (const float*)d_in[0];
    const float* fr   = (const float*)d_in[1];
    const float* wdkv = (const float*)d_in[3];
    const float* wuk  = (const float*)d_in[4];
    const float* wuv  = (const float*)d_in[5];
    const float* wdq  = (const float*)d_in[6];
    const float* wuq  = (const float*)d_in[7];
    const float* wqr  = (const float*)d_in[8];
    const float* wkr  = (const float*)d_in[9];
    const float* wo   = (const float*)d_in[10];
    float* out = (float*)d_out;

    char* p = (char*)d_ws;
    auto alloc = [&](long long bytes) { char* r = p; p += (bytes + 255) & ~255LL; return r; };
    // Persistent-through-attention buffers first:
    unsigned short* qhb   = (unsigned short*)alloc((long long)NH * T * QK * 2); // 12.6 MB
    unsigned short* khb   = (unsigned short*)alloc((long long)NH * T * QK * 2); // 12.6 MB
    unsigned short* vbh   = (unsigned short*)alloc((long long)NH * T * DH * 2); //  8.4 MB
    float*          zrow  = (float*)alloc((long long)NH * T * 4);
    unsigned short* vtb   = (unsigned short*)alloc((long long)NH * T * DH * 2); //  8.4 MB
    unsigned short* Pbuf  = (unsigned short*)alloc(PH * NH * 2);                // 69.2 MB
    // Early-phase buffers overlay the P region (all dead before row_stats_p):
    char* q = (char*)Pbuf;
    auto sub = [&](long long bytes) { char* r = q; q += (bytes + 255) & ~255LL; return r; };
    unsigned short* hb    = (unsigned short*)sub(SZ_H * 2);
    unsigned short* dkvb  = (unsigned short*)sub(SZ_DKV * 2);   // dqb must follow dkvb
    unsigned short* dqb   = (unsigned short*)sub(SZ_DQ * 2);    // contiguously (merged B)
    unsigned short* ukvb  = (unsigned short*)sub((SZ_UK + SZ_UV) * 2); // [n][256][512]
    unsigned short* wqall = (unsigned short*)sub((SZ_UQ + SZ_QR) * 2); // [n][192][512]
    unsigned short* krb   = (unsigned short*)sub(SZ_KR * 2);
    unsigned short* ckvq  = (unsigned short*)sub((long long)T * 1024 * 2); // [t][ckv|cq]
    float*          krt   = (float*)sub((long long)T * DRH * 4 * 4);      // 4 split-K partials
    // Late overlays:
    unsigned short* pvp0  = qhb;   // qhb dead after row_stats_p
    unsigned short* pvp1  = khb;   // khb dead after row_stats_p
    unsigned short* attn2 = pvp0;  // sum_cast2 in-place into partial 0
    unsigned short* wob   = vtb;   // vtb dead after pv_gemm

    cast_all<<<dim3((unsigned)(C8 / 1024)), 256, 0, stream>>>(
        h, wdkv, wuk, wuv, wdq, wuq, wqr, wkr, hb, dkvb, dqb, ukvb, wqall, krb, zrow);

    // merged down-proj: ckvq[t][0:512]=c_kv, [512:1024]=c_q  (64x64 tiles -> 512 blocks)
    gemm_bf16<64,64,32,32,true><<<dim3(T/64, 1024/64, 1), 256, 0, stream>>>(
        hb, dkvb, ckvq, D, D, D, 1024, 0, 0, nullptr, 0, 0);
    // k_r down-proj, split-K x4 -> fp32 partials (summed in rope_qk)
    gemm_bf16<64,64,32,32,false,true><<<dim3(T/64, 1, 4), 256, 0, stream>>>(
        hb, krb, krt, D/4, D, D, DRH, 0, (long long)T * DRH, nullptr, 0, 0);
    // MERGED k_c / v_c up-proj: A = ckvq cols 0:512, B = ukvb[n][256][512].
    gemm_bf16<64,128,32,64,true,false,true><<<dim3(T/64, 2, NH), 256, 0, stream>>>(
        ckvq, ukvb, khb, DC, 1024, DC, QK, (long long)256 * DC, (long long)T * QK,
        vbh, DH, (long long)T * DH);
    // merged q up-proj: N=192 over per-head wqall (A = ckvq cols 512:1024)
    gemm_bf16<128,64,32,64,true><<<dim3(T/128, 3, NH), 256, 0, stream>>>(
        ckvq + DC, wqall, qhb, DC, 1024, DC, QK, (long long)192 * DC, (long long)T * QK,
        nullptr, 0, 0);

    rope_qk<<<dim3((NH * T * 32 + T * 32) / 256), 256, 0, stream>>>(qhb, krt, khb, fr);

    row_stats_p<<<dim3(2048), 256, 0, stream>>>(qhb, khb, zrow, Pbuf);
    vtrans<<<dim3(T/32, DH/32, NH), 256, 0, stream>>>(vbh, zrow, vtb);
    pv_gemm<<<dim3(512), 256, 0, stream>>>(Pbuf, vtb, pvp0, pvp1);

    epilogue_prep<<<dim3(D + T * D / 2048), 256, 0, stream>>>(wo, wob, pvp0, pvp1, attn2);

    gemm_bf16<64,128,32,64,false><<<dim3(T/64, D/128, 1), 256, 0, stream>>>(
        attn2, wob, out, D, D, D, D, 0, 0, nullptr, 0, 0);
}

// Round 12
// 299.916 us; speedup vs baseline: 1.0353x; 1.0353x over previous
//
#include <hip/hip_runtime.h>
#include <hip/hip_bf16.h>
#include <math.h>

// MLA forward, bf16 MFMA pipeline v19.
//  v19 = v17 (measured champion, 304.8us) + the one benign v18 piece:
//   - wo_permute + sum_cast2 merged into epilogue_prep (1 dispatch saved).
//   - GEMM loop REVERTED to v17's 2-phase __syncthreads dbuf: v18's counted-vmcnt
//     3-buffer pipeline was neutral on these latency-bound K=512 GEMMs (T4 needs
//     8-phase interleave to pay), and its inline-asm perturbed the UNCHANGED
//     row_stats_p's codegen 45.4->52.6us (rule #19 co-compilation context).
//  Kept: v13 row_stats_p (empirical optimum), merged kv up-proj (MERGEKV),
//  zrow-in-cast_all, rope_qk, pair-balanced 2-chunk pv_gemm, XOR LDS swizzle,
//  split-K krt, 64x64 down-proj, triangle-packed P^T, 1/z in V, overlays.

namespace {

constexpr int T   = 2048;
constexpr int D   = 2048;
constexpr int NH  = 16;
constexpr int DH  = 128;
constexpr int DRH = 64;
constexpr int DC  = 512;
constexpr int QK  = 192;
constexpr float SCL2E = 0.07216878364870322f * 1.4426950408889634f; // (1/sqrt(192))*log2(e)

// triangle-packed P^T per head: tile j (l in [64j,64j+64)) has row length Lj=2048-64j,
// tile offset OJ(j) = 2048*j*(65-j); per-head size PH = OJ(32).
constexpr long long PH = 2048LL * 32 * 33;  // 2,162,688 shorts

typedef __attribute__((ext_vector_type(8))) short short8;
typedef __attribute__((ext_vector_type(4))) float f32x4;

#define MFMA16(a, b, c) __builtin_amdgcn_mfma_f32_16x16x32_bf16((a), (b), (c), 0, 0, 0)

__device__ __forceinline__ unsigned short f2b(float x) {   // round-to-nearest-even
    unsigned u = __float_as_uint(x);
    unsigned r = (u + 0x7FFFu + ((u >> 16) & 1u)) >> 16;
    return (unsigned short)r;
}
__device__ __forceinline__ unsigned short f2bt(float x) {  // truncate (1 VALU op)
    return (unsigned short)(__float_as_uint(x) >> 16);
}
__device__ __forceinline__ float b2f(unsigned short s) {
    return __uint_as_float(((unsigned)s) << 16);
}

typedef __attribute__((address_space(1))) const unsigned int* gas_t;
typedef __attribute__((address_space(3))) unsigned int* las_t;
__device__ __forceinline__ void async16(const unsigned short* g, unsigned short* l) {
    __builtin_amdgcn_global_load_lds((gas_t)(const void*)g, (las_t)(void*)l, 16, 0, 0);
}

// ---------------- fused fp32 -> bf16 cast/repack of h + 7 weight tensors ----------------
constexpr long long SZ_H    = (long long)T * D;
constexpr long long SZ_DKV  = (long long)DC * D;
constexpr long long SZ_UK   = (long long)DH * NH * DC;
constexpr long long SZ_UV   = SZ_UK;
constexpr long long SZ_DQ   = SZ_DKV;
constexpr long long SZ_UQ   = SZ_UK;
constexpr long long SZ_QR   = (long long)DRH * NH * DC;
constexpr long long SZ_KR   = (long long)DRH * D;
constexpr long long C0 = SZ_H;
constexpr long long C1 = C0 + SZ_DKV;
constexpr long long C2 = C1 + SZ_UK;
constexpr long long C3 = C2 + SZ_UV;
constexpr long long C4 = C3 + SZ_DQ;
constexpr long long C5 = C4 + SZ_UQ;
constexpr long long C6 = C5 + SZ_QR;
constexpr long long C7 = C6 + SZ_KR;   // 10485760
constexpr long long C8 = C7 + 32768;   // + zrow (NH*T floats) zero-fill

__global__ __launch_bounds__(256) void cast_all(
    const float* __restrict__ h,   const float* __restrict__ wdkv,
    const float* __restrict__ wuk, const float* __restrict__ wuv,
    const float* __restrict__ wdq, const float* __restrict__ wuq,
    const float* __restrict__ wqr, const float* __restrict__ wkr,
    unsigned short* __restrict__ hb,   unsigned short* __restrict__ dkvb,
    unsigned short* __restrict__ dqb,  unsigned short* __restrict__ ukvb,
    unsigned short* __restrict__ wqall, unsigned short* __restrict__ krb,
    float* __restrict__ zrow)
{
    long long i4 = ((long long)blockIdx.x * 256 + threadIdx.x) * 4;
    const float* src; unsigned short* dst; long long soff, doff;
    if      (i4 < C0) { src = h;    dst = hb;   soff = i4;      doff = soff; }
    else if (i4 < C1) { src = wdkv; dst = dkvb; soff = i4 - C0; doff = soff; }
    else if (i4 < C2) { // wuk [128][16][512] -> ukvb[n][256][512] rows 0:128
        src = wuk; dst = ukvb; soff = i4 - C1;
        long long e = soff >> 13, n = (soff >> 9) & 15, c = soff & 511;
        doff = n * 131072 + e * 512 + c;
    }
    else if (i4 < C3) { // wuv [128][16][512] -> ukvb[n][256][512] rows 128:256
        src = wuv; dst = ukvb; soff = i4 - C2;
        long long e = soff >> 13, n = (soff >> 9) & 15, c = soff & 511;
        doff = n * 131072 + (128 + e) * 512 + c;
    }
    else if (i4 < C4) { src = wdq;  dst = dqb;  soff = i4 - C3; doff = soff; }
    else if (i4 < C5) { // wuq [128][16][512] -> wqall[n][192][512] rows 0:128
        src = wuq; dst = wqall; soff = i4 - C4;
        long long e = soff >> 13, n = (soff >> 9) & 15, c = soff & 511;
        doff = n * 98304 + e * 512 + c;
    }
    else if (i4 < C6) { // wqr [64][16][512] -> wqall[n][192][512] rows 128:192
        src = wqr; dst = wqall; soff = i4 - C5;
        long long e = soff >> 13, n = (soff >> 9) & 15, c = soff & 511;
        doff = n * 98304 + (128 + e) * 512 + c;
    }
    else if (i4 < C7) { src = wkr;  dst = krb;  soff = i4 - C6; doff = soff; }
    else {             // zero zrow (replaces hipMemsetAsync)
        float4 z4; z4.x = 0.f; z4.y = 0.f; z4.z = 0.f; z4.w = 0.f;
        *(float4*)(zrow + (i4 - C7)) = z4;
        return;
    }
    float4 v = *(const float4*)(src + soff);
    uint2 pk;
    pk.x = (unsigned)f2b(v.x) | ((unsigned)f2b(v.y) << 16);
    pk.y = (unsigned)f2b(v.z) | ((unsigned)f2b(v.w) << 16);
    *(uint2*)(dst + doff) = pk;
}

// ---------------- bf16 MFMA NT GEMM, double-buffered global_load_lds staging -------
// LDS slot swizzle: slot holds global k-chunk (slot ^ (row>>1)&3); reader fetches
// slot q^((row>>1)&3) -> bank-conflict-free (measured 0).
// Loop = T3-minimum 2-phase: STAGE(next) issued before compute(cur), 1 barrier/step.
// SPLITK: blockIdx.z slices K. MERGEKV: blockIdx.y==1 routes C to C2/ldc2/sC2.
template<int BM, int BN, int WM, int WN, bool OUTB, bool SPLITK = false, bool MERGEKV = false>
__global__ __launch_bounds__(256) void gemm_bf16(
    const unsigned short* __restrict__ A, const unsigned short* __restrict__ B,
    void* __restrict__ C, int K, int lda, int ldb, int ldc,
    long long sB, long long sC,
    void* __restrict__ C2, int ldc2, long long sC2)
{
    constexpr int MT = WM / 16, NT = WN / 16;
    constexpr int WX = BN / WN;
    __shared__ unsigned short As[2][BM * 32];
    __shared__ unsigned short Bs[2][BN * 32];
    const int tid = (int)threadIdx.x;
    const int wave = tid >> 6, lane = tid & 63;
    const int q = lane >> 4, c = lane & 15;
    const int wm = (wave / WX) * WM, wn = (wave % WX) * WN;
    const int m0 = (int)blockIdx.x * BM, n0 = (int)blockIdx.y * BN;

    const unsigned short* Ab;
    const unsigned short* Bb;
    long long cb;
    void* Cp = C;
    int ldcl = ldc;
    int n0c = n0;
    if constexpr (SPLITK) {
        int koff = (int)blockIdx.z * K;
        Ab = A + koff;
        Bb = B + koff;
        cb = (long long)blockIdx.z * sC;
    } else {
        Ab = A;
        Bb = B + (long long)blockIdx.z * sB;
        cb = (long long)blockIdx.z * sC;
    }
    if constexpr (MERGEKV) {
        if (blockIdx.y == 1) {
            Cp = C2; ldcl = ldc2; n0c = 0;
            cb = (long long)blockIdx.z * sC2;
        }
    }

    f32x4 acc[MT][NT];
#pragma unroll
    for (int i = 0; i < MT; ++i)
#pragma unroll
        for (int j = 0; j < NT; ++j) acc[i][j] = (f32x4){0.f, 0.f, 0.f, 0.f};

    auto STAGE = [&](int buf, int k0) {
#pragma unroll
        for (int i = 0; i < BM / 64; ++i) {
            int ch = tid + i * 256;
            async16(&Ab[(long long)(m0 + (ch >> 2)) * lda + k0 + (((ch & 3) ^ ((ch >> 3) & 3)) * 8)],
                    &As[buf][(i * 256 + wave * 64) * 8]);
        }
#pragma unroll
        for (int i = 0; i < BN / 64; ++i) {
            int ch = tid + i * 256;
            async16(&Bb[(long long)(n0 + (ch >> 2)) * ldb + k0 + (((ch & 3) ^ ((ch >> 3) & 3)) * 8)],
                    &Bs[buf][(i * 256 + wave * 64) * 8]);
        }
    };

    STAGE(0, 0);
    __syncthreads();                       // drains vmcnt(0): buf0 ready
    int cur = 0;
    for (int k0 = 0; k0 < K; k0 += 32) {
        if (k0 + 32 < K) STAGE(cur ^ 1, k0 + 32);   // prefetch overlaps compute
        short8 af[MT], bfr[NT];
#pragma unroll
        for (int i = 0; i < MT; ++i) {
            int row = wm + i * 16 + c;
            af[i] = *(const short8*)&As[cur][row * 32 + (q ^ ((row >> 1) & 3)) * 8];
        }
#pragma unroll
        for (int j = 0; j < NT; ++j) {
            int row = wn + j * 16 + c;
            bfr[j] = *(const short8*)&Bs[cur][row * 32 + (q ^ ((row >> 1) & 3)) * 8];
        }
#pragma unroll
        for (int i = 0; i < MT; ++i)
#pragma unroll
            for (int j = 0; j < NT; ++j)
                acc[i][j] = MFMA16(af[i], bfr[j], acc[i][j]);
        __syncthreads();                   // next buf staged; cur free to overwrite
        cur ^= 1;
    }
#pragma unroll
    for (int i = 0; i < MT; ++i)
#pragma unroll
        for (int j = 0; j < NT; ++j) {
            int rbase = m0 + wm + i * 16 + q * 4;
            int col = n0c + wn + j * 16 + c;
#pragma unroll
            for (int rr = 0; rr < 4; ++rr) {
                long long off = cb + (long long)(rbase + rr) * ldcl + col;
                if (OUTB) ((unsigned short*)Cp)[off] = f2b(acc[i][j][rr]);
                else      ((float*)Cp)[off] = acc[i][j][rr];
            }
        }
}

// ---------------- RoPE (merged q + k) ----------------
__global__ __launch_bounds__(256) void rope_qk(unsigned short* __restrict__ qh,
                                               const float* __restrict__ krtp,
                                               unsigned short* __restrict__ kh,
                                               const float* __restrict__ fr)
{
    int idx = (int)blockIdx.x * 256 + (int)threadIdx.x;
    if (idx < NH * T * 32) {               // ---- rope_q ----
        int j = idx & 31;
        int t = (idx >> 5) & (T - 1);
        int n = idx >> 16;
        float sn, cs;
        sincosf(fr[t * 32 + j], &sn, &cs);
        long long base = ((long long)(n * T + t)) * QK + 128 + j;
        float x0 = b2f(qh[base]);
        float x1 = b2f(qh[base + 32]);
        qh[base]      = f2b(x0 * cs - x1 * sn);
        qh[base + 32] = f2b(x0 * sn + x1 * cs);
    } else {                               // ---- rope_k ----
        idx -= NH * T * 32;
        int j = idx & 31;
        int t = idx >> 5;
        float sn, cs;
        sincosf(fr[t * 32 + j], &sn, &cs);
        float x0 = 0.f, x1 = 0.f;
#pragma unroll
        for (int pth = 0; pth < 4; ++pth) {
            x0 += krtp[pth * (T * 64) + t * 64 + j];
            x1 += krtp[pth * (T * 64) + t * 64 + 32 + j];
        }
        unsigned short y0 = f2b((x0 * cs - x1 * sn) * (1.0f / 16.0f));
        unsigned short y1 = f2b((x0 * sn + x1 * cs) * (1.0f / 16.0f));
#pragma unroll
        for (int n = 0; n < NH; ++n) {
            long long base = ((long long)(n * T + t)) * QK + 128 + j;
            kh[base]      = y0;
            kh[base + 32] = y1;
        }
    }
}

// vbh[n][t][e] -> vt[n][e][t] scaled by 1/z_t
__global__ __launch_bounds__(256) void vtrans(const unsigned short* __restrict__ vbh,
                                              const float* __restrict__ zrow,
                                              unsigned short* __restrict__ vt)
{
    __shared__ unsigned short ts[32][33];
    __shared__ float zi[32];
    int t0 = (int)blockIdx.x * 32, e0 = (int)blockIdx.y * 32, n = (int)blockIdx.z;
    int tid = (int)threadIdx.x;
    if (tid < 32) zi[tid] = 1.0f / zrow[n * T + t0 + tid];
    int r = tid >> 3, cq = (tid & 7) * 4;
    const unsigned short* src = vbh + ((long long)(n * T + t0 + r)) * DH + e0 + cq;
#pragma unroll
    for (int i = 0; i < 4; ++i) ts[r][cq + i] = src[i];
    __syncthreads();
    unsigned short* dst = vt + ((long long)(n * DH + e0 + r)) * T + t0 + cq;
#pragma unroll
    for (int i = 0; i < 4; ++i) dst[i] = f2b(b2f(ts[cq + i][r]) * zi[cq + i]);
}

// ---------------- Pass A: z_t AND P^T store (single QK^T) ----------------
// v10/v13 implementation (empirical local optimum: 45.4us, VGPR 92). Operand-
// swapped MFMA: D row = l (A = K rows), D col = t (B = Q rows). P^T =
// bf16_trunc(exp2(s*scl)) stored triangle-packed per head; z via atomics.
// 1D grid 2048, XCD-swizzled, longest-first (tbi=31 first), 4 l-chunks.
__global__ __launch_bounds__(256) void row_stats_p(const unsigned short* __restrict__ qh,
                                                   const unsigned short* __restrict__ kh,
                                                   float* __restrict__ zrow,
                                                   unsigned short* __restrict__ Pbuf)
{
    int id = (int)blockIdx.x;
    int n = (id & 7) * 2 + ((id >> 3) & 1);
    int rest = id >> 4;                      // 0..127
    int tbi = 31 - (rest & 31);              // longest (tbi=31) first
    int chunk = rest >> 5;                   // 0..3
    int tid = (int)threadIdx.x, wave = tid >> 6, lane = tid & 63;
    int q = lane >> 4, c = lane & 15;
    int tw = tbi * 64 + wave * 16;

    __shared__ unsigned short Ks[64 * 200];

    // Q fragments for the wave's 16 t-rows (B operand)
    const unsigned short* qp = qh + ((long long)(n * T + tw + c)) * QK;
    short8 qf[6];
#pragma unroll
    for (int f = 0; f < 6; ++f) qf[f] = *(const short8*)(qp + f * 32 + q * 8);

    float z = 0.f;                           // z partial for t = tw + c
    const unsigned short* kbase = kh + (long long)n * T * QK;
    unsigned short* Ph = Pbuf + (long long)n * PH;

    short8 kreg[6];
    int lt = chunk;
    if (lt <= tbi) {
        const unsigned short* kp = kbase + (long long)lt * 64 * QK;
#pragma unroll
        for (int i = 0; i < 6; ++i) {
            int ch = tid + i * 256;
            int r = ch / 24, cc = ch - r * 24;
            kreg[i] = *(const short8*)(kp + r * QK + cc * 8);
        }
    }
    for (; lt <= tbi; lt += 4) {
        __syncthreads();
#pragma unroll
        for (int i = 0; i < 6; ++i) {
            int ch = tid + i * 256;
            int r = ch / 24, cc = ch - r * 24;
            *(short8*)&Ks[r * 200 + cc * 8] = kreg[i];
        }
        __syncthreads();
        if (lt + 4 <= tbi) {
            const unsigned short* kp = kbase + (long long)(lt + 4) * 64 * QK;
#pragma unroll
            for (int i = 0; i < 6; ++i) {
                int ch = tid + i * 256;
                int r = ch / 24, cc = ch - r * 24;
                kreg[i] = *(const short8*)(kp + r * QK + cc * 8);
            }
        }
        f32x4 d[4];
#pragma unroll
        for (int ls = 0; ls < 4; ++ls) d[ls] = (f32x4){0.f, 0.f, 0.f, 0.f};
        __builtin_amdgcn_s_setprio(1);
#pragma unroll
        for (int f = 0; f < 6; ++f)
#pragma unroll
            for (int ls = 0; ls < 4; ++ls) {
                short8 ka = *(const short8*)&Ks[(ls * 16 + c) * 200 + f * 32 + q * 8];
                d[ls] = MFMA16(ka, qf[f], d[ls]);
            }
        __builtin_amdgcn_s_setprio(0);
        // P^T tile base: tile lt, row (l-64lt) = ls*16+q*4+r, col (t-64lt)
        int L = T - lt * 64;                 // packed row length for tile lt
        unsigned short* pb = Ph + (long long)2048 * lt * (65 - lt)
                             + (long long)(q * 4) * L + (tbi - lt) * 64 + wave * 16 + c;
        if (lt == tbi) {                     // diagonal tile: mask l > t, store zeros
            int tl = wave * 16 + c;
#pragma unroll
            for (int ls = 0; ls < 4; ++ls)
#pragma unroll
                for (int r = 0; r < 4; ++r) {
                    float pe = exp2f(d[ls][r] * SCL2E);
                    bool ok = (ls * 16 + q * 4 + r) <= tl;
                    z += ok ? pe : 0.f;
                    pb[(ls * 16 + r) * L] = ok ? f2bt(pe) : (unsigned short)0;
                }
        } else {
#pragma unroll
            for (int ls = 0; ls < 4; ++ls)
#pragma unroll
                for (int r = 0; r < 4; ++r) {
                    float pe = exp2f(d[ls][r] * SCL2E);
                    z += pe;
                    pb[(ls * 16 + r) * L] = f2bt(pe);
                }
        }
    }
    // reduce z over the q dimension (lanes c, c+16, c+32, c+48 share t = tw+c)
    z += __shfl_xor(z, 16);
    z += __shfl_xor(z, 32);
    if (q == 0) atomicAdd(&zrow[n * T + tw + c], z);
}

// ---------------- Pass B: out[l][n*128+e] = sum_t P^T[l][t] * V'[e][t] ----------------
// NT GEMM on triangle-packed P^T (A) and vt (B), dbuf staging, pair-balanced:
// block = (head, pair pr, chunk of 2) processes l-tiles {pr, 31-pr} -> 33 t-tiles
// per pair. 2 chunks -> 2 bf16 partials. 512 uniform blocks = 2/CU.
__global__ __launch_bounds__(256) void pv_gemm(const unsigned short* __restrict__ Pbuf,
                                               const unsigned short* __restrict__ vt,
                                               unsigned short* __restrict__ p0,
                                               unsigned short* __restrict__ p1)
{
    __shared__ unsigned short As[2][64 * 32];
    __shared__ unsigned short Bs[2][128 * 32];
    int id = (int)blockIdx.x;
    int n = (id & 7) * 2 + ((id >> 3) & 1);
    int rest = id >> 4;                      // 0..31
    int pr = rest & 15;                      // pair index 0..15
    int chunk = (rest >> 4) & 1;             // 0..1
    const int tid = (int)threadIdx.x, wave = tid >> 6, lane = tid & 63;
    const int q = lane >> 4, c = lane & 15;
    const int wm = (wave >> 1) * 32, wn = (wave & 1) * 64;
    unsigned short* op = chunk ? p1 : p0;

#pragma unroll
    for (int ph = 0; ph < 2; ++ph) {
        int j = ph ? (31 - pr) : pr;
        int m0 = j * 64;
        int L = T - m0;                      // packed lda and K extent
        int ntile = 32 - j;
        const unsigned short* A = Pbuf + (long long)n * PH + (long long)2048 * j * (65 - j);
        const unsigned short* B = vt + (long long)n * DH * T + m0;

        f32x4 acc[2][4];
#pragma unroll
        for (int i = 0; i < 2; ++i)
#pragma unroll
            for (int jj = 0; jj < 4; ++jj) acc[i][jj] = (f32x4){0.f, 0.f, 0.f, 0.f};

        int tcnt = (chunk < ntile) ? (((ntile - 1 - chunk) >> 1) + 1) : 0;
        int nsteps = tcnt * 2;

        auto STAGE = [&](int buf, int k0) {
            async16(&A[(long long)(tid >> 2) * L + k0 + (((tid & 3) ^ ((tid >> 3) & 3)) * 8)],
                    &As[buf][wave * 512]);
#pragma unroll
            for (int i = 0; i < 2; ++i) {
                int ch = tid + i * 256;
                async16(&B[(long long)(ch >> 2) * T + k0 + (((ch & 3) ^ ((ch >> 3) & 3)) * 8)],
                        &Bs[buf][(i * 256 + wave * 64) * 8]);
            }
        };
        auto K0 = [&](int s) { return (chunk + ((s >> 1) << 1)) * 64 + (s & 1) * 32; };

        if (nsteps > 0) STAGE(0, K0(0));
        __syncthreads();
        int cur = 0;
        for (int s = 0; s < nsteps; ++s) {
            if (s + 1 < nsteps) STAGE(cur ^ 1, K0(s + 1));
            short8 af[2], bfr[4];
#pragma unroll
            for (int i = 0; i < 2; ++i) {
                int row = wm + i * 16 + c;
                af[i] = *(const short8*)&As[cur][row * 32 + (q ^ ((row >> 1) & 3)) * 8];
            }
#pragma unroll
            for (int jj = 0; jj < 4; ++jj) {
                int row = wn + jj * 16 + c;
                bfr[jj] = *(const short8*)&Bs[cur][row * 32 + (q ^ ((row >> 1) & 3)) * 8];
            }
#pragma unroll
            for (int i = 0; i < 2; ++i)
#pragma unroll
                for (int jj = 0; jj < 4; ++jj)
                    acc[i][jj] = MFMA16(af[i], bfr[jj], acc[i][jj]);
            __syncthreads();
            cur ^= 1;
        }
        // always write (zeros when this chunk has no tiles) — partials are summed
#pragma unroll
        for (int i = 0; i < 2; ++i)
#pragma unroll
            for (int jj = 0; jj < 4; ++jj) {
                int rbase = m0 + wm + i * 16 + q * 4;
                int col = n * 128 + wn + jj * 16 + c;
#pragma unroll
                for (int rr = 0; rr < 4; ++rr)
                    op[(long long)(rbase + rr) * D + col] = f2b(acc[i][jj][rr]);
            }
        __syncthreads();                   // LDS reuse across phases
    }
}

// Merged epilogue prep: blocks [0,D) -> wo_permute; blocks [D, D + T*D/2048) -> sum_cast2.
// wob[d][n*128 + e] = bf16(wo[d][e*16 + n]); attn2 = bf16(p0 + p1) (o may alias a).
__global__ __launch_bounds__(256) void epilogue_prep(const float* __restrict__ wo,
                                                     unsigned short* __restrict__ wob,
                                                     const unsigned short* a,
                                                     const unsigned short* b,
                                                     unsigned short* o)
{
    __shared__ float row[2048];
    int bid = (int)blockIdx.x;
    if (bid < D) {                         // ---- wo_permute ----
        const float* src = wo + (long long)bid * 2048;
#pragma unroll
        for (int i = 0; i < 8; ++i) row[threadIdx.x + i * 256] = src[threadIdx.x + i * 256];
        __syncthreads();
        unsigned short* dst = wob + (long long)bid * 2048;
#pragma unroll
        for (int i = 0; i < 8; ++i) {
            int j = threadIdx.x + i * 256;
            int n = j >> 7, e = j & 127;
            dst[j] = f2b(row[e * 16 + n]);
        }
    } else {                               // ---- sum_cast2 ----
        long long i = ((long long)(bid - D) * 256 + threadIdx.x) * 8;
        short8 va = *(const short8*)(a + i);
        short8 vb = *(const short8*)(b + i);
        short8 vo;
#pragma unroll
        for (int j = 0; j < 8; ++j)
            vo[j] = (short)f2b(b2f((unsigned short)va[j]) + b2f((unsigned short)vb[j]));
        *(short8*)(o + i) = vo;
    }
}

} // namespace

extern "C" void kernel_launch(void* const* d_in, const int* in_sizes, int n_in,
                              void* d_out, int out_size, void* d_ws, size_t ws_size,
                              hipStream_t stream)
{
    (void)in_sizes; (void)n_in; (void)out_size; (void)ws_size;
    const float* h    = (const float*)d_in[0];
    const float* fr   = (const float*)d_in[1];
    const float* wdkv = (const float*)d_in[3];
    const float* wuk  = (const float*)d_in[4];
    const float* wuv  = (const float*)d_in[5];
    const float* wdq  = (const float*)d_in[6];
    const float* wuq  = (const float*)d_in[7];
    const float* wqr  = (const float*)d_in[8];
    const float* wkr  = (const float*)d_in[9];
    const float* wo   = (const float*)d_in[10];
    float* out = (float*)d_out;

    char* p = (char*)d_ws;
    auto alloc = [&](long long bytes) { char* r = p; p += (bytes + 255) & ~255LL; return r; };
    // Persistent-through-attention buffers first:
    unsigned short* qhb   = (unsigned short*)alloc((long long)NH * T * QK * 2); // 12.6 MB
    unsigned short* khb   = (unsigned short*)alloc((long long)NH * T * QK * 2); // 12.6 MB
    unsigned short* vbh   = (unsigned short*)alloc((long long)NH * T * DH * 2); //  8.4 MB
    float*          zrow  = (float*)alloc((long long)NH * T * 4);
    unsigned short* vtb   = (unsigned short*)alloc((long long)NH * T * DH * 2); //  8.4 MB
    unsigned short* Pbuf  = (unsigned short*)alloc(PH * NH * 2);                // 69.2 MB
    // Early-phase buffers overlay the P region (all dead before row_stats_p):
    char* q = (char*)Pbuf;
    auto sub = [&](long long bytes) { char* r = q; q += (bytes + 255) & ~255LL; return r; };
    unsigned short* hb    = (unsigned short*)sub(SZ_H * 2);
    unsigned short* dkvb  = (unsigned short*)sub(SZ_DKV * 2);   // dqb must follow dkvb
    unsigned short* dqb   = (unsigned short*)sub(SZ_DQ * 2);    // contiguously (merged B)
    unsigned short* ukvb  = (unsigned short*)sub((SZ_UK + SZ_UV) * 2); // [n][256][512]
    unsigned short* wqall = (unsigned short*)sub((SZ_UQ + SZ_QR) * 2); // [n][192][512]
    unsigned short* krb   = (unsigned short*)sub(SZ_KR * 2);
    unsigned short* ckvq  = (unsigned short*)sub((long long)T * 1024 * 2); // [t][ckv|cq]
    float*          krt   = (float*)sub((long long)T * DRH * 4 * 4);      // 4 split-K partials
    // Late overlays:
    unsigned short* pvp0  = qhb;   // qhb dead after row_stats_p
    unsigned short* pvp1  = khb;   // khb dead after row_stats_p
    unsigned short* attn2 = pvp0;  // sum_cast2 in-place into partial 0
    unsigned short* wob   = vtb;   // vtb dead after pv_gemm

    cast_all<<<dim3((unsigned)(C8 / 1024)), 256, 0, stream>>>(
        h, wdkv, wuk, wuv, wdq, wuq, wqr, wkr, hb, dkvb, dqb, ukvb, wqall, krb, zrow);

    // merged down-proj: ckvq[t][0:512]=c_kv, [512:1024]=c_q  (64x64 tiles -> 512 blocks)
    gemm_bf16<64,64,32,32,true><<<dim3(T/64, 1024/64, 1), 256, 0, stream>>>(
        hb, dkvb, ckvq, D, D, D, 1024, 0, 0, nullptr, 0, 0);
    // k_r down-proj, split-K x4 -> fp32 partials (summed in rope_qk)
    gemm_bf16<64,64,32,32,false,true><<<dim3(T/64, 1, 4), 256, 0, stream>>>(
        hb, krb, krt, D/4, D, D, DRH, 0, (long long)T * DRH, nullptr, 0, 0);
    // MERGED k_c / v_c up-proj: A = ckvq cols 0:512, B = ukvb[n][256][512].
    gemm_bf16<64,128,32,64,true,false,true><<<dim3(T/64, 2, NH), 256, 0, stream>>>(
        ckvq, ukvb, khb, DC, 1024, DC, QK, (long long)256 * DC, (long long)T * QK,
        vbh, DH, (long long)T * DH);
    // merged q up-proj: N=192 over per-head wqall (A = ckvq cols 512:1024)
    gemm_bf16<128,64,32,64,true><<<dim3(T/128, 3, NH), 256, 0, stream>>>(
        ckvq + DC, wqall, qhb, DC, 1024, DC, QK, (long long)192 * DC, (long long)T * QK,
        nullptr, 0, 0);

    rope_qk<<<dim3((NH * T * 32 + T * 32) / 256), 256, 0, stream>>>(qhb, krt, khb, fr);

    row_stats_p<<<dim3(2048), 256, 0, stream>>>(qhb, khb, zrow, Pbuf);
    vtrans<<<dim3(T/32, DH/32, NH), 256, 0, stream>>>(vbh, zrow, vtb);
    pv_gemm<<<dim3(512), 256, 0, stream>>>(Pbuf, vtb, pvp0, pvp1);

    epilogue_prep<<<dim3(D + T * D / 2048), 256, 0, stream>>>(wo, wob, pvp0, pvp1, attn2);

    gemm_bf16<64,128,32,64,false><<<dim3(T/64, D/128, 1), 256, 0, stream>>>(
        attn2, wob, out, D, D, D, D, 0, 0, nullptr, 0, 0);
}

// Round 13
// 294.044 us; speedup vs baseline: 1.0560x; 1.0200x over previous
//
#include <hip/hip_runtime.h>
#include <hip/hip_bf16.h>
#include <math.h>

// MLA forward, bf16 MFMA pipeline v20.
//  v20 = v19 (champion, 299.9us) with concurrency merges of independent dispatches:
//   - down-proj + k_r down-proj fused into ONE dispatch (FUSEKR): grid (32,20,1);
//     y<16 -> ckvq (K=2048), y>=16 -> krt split-K slice z=y-16 (K=512, fp32).
//     Both only read hb + weights; previously serialized, krt now free.
//   - kv up-proj + q up-proj fused into up_proj_fused: grid (32,7,16), 64x64
//     tiles; y<2 -> khb k_c, y in[2,4) -> vbh v_c, y in[4,7) -> qhb q_c|q_r.
//     Both only read ckvq; 3584 blocks = 14/CU, one launch.
//   Dispatches 11 -> 9. No inline asm (v18 rule-19 lesson).
//  Kept: v13 row_stats_p (empirical optimum), 2-phase dbuf GEMM loops, XOR LDS
//  swizzle, zrow-in-cast_all, rope_qk, pair-balanced 2-chunk pv_gemm,
//  epilogue_prep, triangle-packed P^T, 1/z folded into V, overlays.

namespace {

constexpr int T   = 2048;
constexpr int D   = 2048;
constexpr int NH  = 16;
constexpr int DH  = 128;
constexpr int DRH = 64;
constexpr int DC  = 512;
constexpr int QK  = 192;
constexpr float SCL2E = 0.07216878364870322f * 1.4426950408889634f; // (1/sqrt(192))*log2(e)

// triangle-packed P^T per head: tile j (l in [64j,64j+64)) has row length Lj=2048-64j,
// tile offset OJ(j) = 2048*j*(65-j); per-head size PH = OJ(32).
constexpr long long PH = 2048LL * 32 * 33;  // 2,162,688 shorts

typedef __attribute__((ext_vector_type(8))) short short8;
typedef __attribute__((ext_vector_type(4))) float f32x4;

#define MFMA16(a, b, c) __builtin_amdgcn_mfma_f32_16x16x32_bf16((a), (b), (c), 0, 0, 0)

__device__ __forceinline__ unsigned short f2b(float x) {   // round-to-nearest-even
    unsigned u = __float_as_uint(x);
    unsigned r = (u + 0x7FFFu + ((u >> 16) & 1u)) >> 16;
    return (unsigned short)r;
}
__device__ __forceinline__ unsigned short f2bt(float x) {  // truncate (1 VALU op)
    return (unsigned short)(__float_as_uint(x) >> 16);
}
__device__ __forceinline__ float b2f(unsigned short s) {
    return __uint_as_float(((unsigned)s) << 16);
}

typedef __attribute__((address_space(1))) const unsigned int* gas_t;
typedef __attribute__((address_space(3))) unsigned int* las_t;
__device__ __forceinline__ void async16(const unsigned short* g, unsigned short* l) {
    __builtin_amdgcn_global_load_lds((gas_t)(const void*)g, (las_t)(void*)l, 16, 0, 0);
}

// ---------------- fused fp32 -> bf16 cast/repack of h + 7 weight tensors ----------------
constexpr long long SZ_H    = (long long)T * D;
constexpr long long SZ_DKV  = (long long)DC * D;
constexpr long long SZ_UK   = (long long)DH * NH * DC;
constexpr long long SZ_UV   = SZ_UK;
constexpr long long SZ_DQ   = SZ_DKV;
constexpr long long SZ_UQ   = SZ_UK;
constexpr long long SZ_QR   = (long long)DRH * NH * DC;
constexpr long long SZ_KR   = (long long)DRH * D;
constexpr long long C0 = SZ_H;
constexpr long long C1 = C0 + SZ_DKV;
constexpr long long C2 = C1 + SZ_UK;
constexpr long long C3 = C2 + SZ_UV;
constexpr long long C4 = C3 + SZ_DQ;
constexpr long long C5 = C4 + SZ_UQ;
constexpr long long C6 = C5 + SZ_QR;
constexpr long long C7 = C6 + SZ_KR;   // 10485760
constexpr long long C8 = C7 + 32768;   // + zrow (NH*T floats) zero-fill

__global__ __launch_bounds__(256) void cast_all(
    const float* __restrict__ h,   const float* __restrict__ wdkv,
    const float* __restrict__ wuk, const float* __restrict__ wuv,
    const float* __restrict__ wdq, const float* __restrict__ wuq,
    const float* __restrict__ wqr, const float* __restrict__ wkr,
    unsigned short* __restrict__ hb,   unsigned short* __restrict__ dkvb,
    unsigned short* __restrict__ dqb,  unsigned short* __restrict__ ukvb,
    unsigned short* __restrict__ wqall, unsigned short* __restrict__ krb,
    float* __restrict__ zrow)
{
    long long i4 = ((long long)blockIdx.x * 256 + threadIdx.x) * 4;
    const float* src; unsigned short* dst; long long soff, doff;
    if      (i4 < C0) { src = h;    dst = hb;   soff = i4;      doff = soff; }
    else if (i4 < C1) { src = wdkv; dst = dkvb; soff = i4 - C0; doff = soff; }
    else if (i4 < C2) { // wuk [128][16][512] -> ukvb[n][256][512] rows 0:128
        src = wuk; dst = ukvb; soff = i4 - C1;
        long long e = soff >> 13, n = (soff >> 9) & 15, c = soff & 511;
        doff = n * 131072 + e * 512 + c;
    }
    else if (i4 < C3) { // wuv [128][16][512] -> ukvb[n][256][512] rows 128:256
        src = wuv; dst = ukvb; soff = i4 - C2;
        long long e = soff >> 13, n = (soff >> 9) & 15, c = soff & 511;
        doff = n * 131072 + (128 + e) * 512 + c;
    }
    else if (i4 < C4) { src = wdq;  dst = dqb;  soff = i4 - C3; doff = soff; }
    else if (i4 < C5) { // wuq [128][16][512] -> wqall[n][192][512] rows 0:128
        src = wuq; dst = wqall; soff = i4 - C4;
        long long e = soff >> 13, n = (soff >> 9) & 15, c = soff & 511;
        doff = n * 98304 + e * 512 + c;
    }
    else if (i4 < C6) { // wqr [64][16][512] -> wqall[n][192][512] rows 128:192
        src = wqr; dst = wqall; soff = i4 - C5;
        long long e = soff >> 13, n = (soff >> 9) & 15, c = soff & 511;
        doff = n * 98304 + (128 + e) * 512 + c;
    }
    else if (i4 < C7) { src = wkr;  dst = krb;  soff = i4 - C6; doff = soff; }
    else {             // zero zrow (replaces hipMemsetAsync)
        float4 z4; z4.x = 0.f; z4.y = 0.f; z4.z = 0.f; z4.w = 0.f;
        *(float4*)(zrow + (i4 - C7)) = z4;
        return;
    }
    float4 v = *(const float4*)(src + soff);
    uint2 pk;
    pk.x = (unsigned)f2b(v.x) | ((unsigned)f2b(v.y) << 16);
    pk.y = (unsigned)f2b(v.z) | ((unsigned)f2b(v.w) << 16);
    *(uint2*)(dst + doff) = pk;
}

// ---------------- bf16 MFMA NT GEMM, double-buffered global_load_lds staging -------
// LDS slot swizzle: slot holds global k-chunk (slot ^ (row>>1)&3); reader fetches
// slot q^((row>>1)&3) -> bank-conflict-free (measured 0).
// Loop = T3-minimum 2-phase: STAGE(next) issued before compute(cur), 1 barrier/step.
// FUSEKR: blockIdx.y>=16 runs the k_r down-proj split-K slice z=y-16 (K=512,
// A/B2 K-window offset z*512, C2 fp32 ldc 64, stride T*64) concurrently.
template<int BM, int BN, int WM, int WN, bool OUTB, bool FUSEKR = false>
__global__ __launch_bounds__(256) void gemm_bf16(
    const unsigned short* __restrict__ A, const unsigned short* __restrict__ B,
    void* __restrict__ C, int K, int lda, int ldb, int ldc,
    void* __restrict__ C2, const unsigned short* __restrict__ B2)
{
    constexpr int MT = WM / 16, NT = WN / 16;
    constexpr int WX = BN / WN;
    __shared__ unsigned short As[2][BM * 32];
    __shared__ unsigned short Bs[2][BN * 32];
    const int tid = (int)threadIdx.x;
    const int wave = tid >> 6, lane = tid & 63;
    const int q = lane >> 4, c = lane & 15;
    const int wm = (wave / WX) * WM, wn = (wave % WX) * WN;
    const int m0 = (int)blockIdx.x * BM;

    const unsigned short* Ab = A;
    const unsigned short* Bb = B;
    void* Cp = C;
    long long cb = 0;
    int ldcl = ldc;
    int n0 = (int)blockIdx.y * BN;
    int Klen = K;
    bool outb = OUTB;
    if constexpr (FUSEKR) {
        if (blockIdx.y >= 16) {
            int z = (int)blockIdx.y - 16;
            Ab = A + z * 512;             // K-window
            Bb = B2 + z * 512;
            Cp = C2; ldcl = 64; n0 = 0;
            cb = (long long)z * (T * 64);
            Klen = 512;
            outb = false;
        }
    }

    f32x4 acc[MT][NT];
#pragma unroll
    for (int i = 0; i < MT; ++i)
#pragma unroll
        for (int j = 0; j < NT; ++j) acc[i][j] = (f32x4){0.f, 0.f, 0.f, 0.f};

    auto STAGE = [&](int buf, int k0) {
#pragma unroll
        for (int i = 0; i < BM / 64; ++i) {
            int ch = tid + i * 256;
            async16(&Ab[(long long)(m0 + (ch >> 2)) * lda + k0 + (((ch & 3) ^ ((ch >> 3) & 3)) * 8)],
                    &As[buf][(i * 256 + wave * 64) * 8]);
        }
#pragma unroll
        for (int i = 0; i < BN / 64; ++i) {
            int ch = tid + i * 256;
            async16(&Bb[(long long)(n0 + (ch >> 2)) * ldb + k0 + (((ch & 3) ^ ((ch >> 3) & 3)) * 8)],
                    &Bs[buf][(i * 256 + wave * 64) * 8]);
        }
    };

    STAGE(0, 0);
    __syncthreads();                       // drains vmcnt(0): buf0 ready
    int cur = 0;
    for (int k0 = 0; k0 < Klen; k0 += 32) {
        if (k0 + 32 < Klen) STAGE(cur ^ 1, k0 + 32);   // prefetch overlaps compute
        short8 af[MT], bfr[NT];
#pragma unroll
        for (int i = 0; i < MT; ++i) {
            int row = wm + i * 16 + c;
            af[i] = *(const short8*)&As[cur][row * 32 + (q ^ ((row >> 1) & 3)) * 8];
        }
#pragma unroll
        for (int j = 0; j < NT; ++j) {
            int row = wn + j * 16 + c;
            bfr[j] = *(const short8*)&Bs[cur][row * 32 + (q ^ ((row >> 1) & 3)) * 8];
        }
#pragma unroll
        for (int i = 0; i < MT; ++i)
#pragma unroll
            for (int j = 0; j < NT; ++j)
                acc[i][j] = MFMA16(af[i], bfr[j], acc[i][j]);
        __syncthreads();                   // next buf staged; cur free to overwrite
        cur ^= 1;
    }
#pragma unroll
    for (int i = 0; i < MT; ++i)
#pragma unroll
        for (int j = 0; j < NT; ++j) {
            int rbase = m0 + wm + i * 16 + q * 4;
            int col = n0 + wn + j * 16 + c;
#pragma unroll
            for (int rr = 0; rr < 4; ++rr) {
                long long off = cb + (long long)(rbase + rr) * ldcl + col;
                if (outb) ((unsigned short*)Cp)[off] = f2b(acc[i][j][rr]);
                else      ((float*)Cp)[off] = acc[i][j][rr];
            }
        }
}

// ---------------- fused k_c / v_c / q up-projections ----------------
// grid (T/64, 7, NH), 64x64 tiles, K = DC = 512.
// y in [0,2): khb cols y*64 (k_c); [2,4): vbh cols (y-2)*64 (v_c);
// [4,7): qhb cols (y-4)*64 (q_c | pre-rope q_r). A = ckvq (cols 0:512 / 512:1024).
__global__ __launch_bounds__(256) void up_proj_fused(
    const unsigned short* __restrict__ ckvq, const unsigned short* __restrict__ ukvb,
    const unsigned short* __restrict__ wqall, unsigned short* __restrict__ khb,
    unsigned short* __restrict__ vbh, unsigned short* __restrict__ qhb)
{
    __shared__ unsigned short As[2][64 * 32];
    __shared__ unsigned short Bs[2][64 * 32];
    const int tid = (int)threadIdx.x;
    const int wave = tid >> 6, lane = tid & 63;
    const int q = lane >> 4, c = lane & 15;
    const int wm = (wave >> 1) * 32, wn = (wave & 1) * 32;
    const int m0 = (int)blockIdx.x * 64;
    const int y = (int)blockIdx.y, n = (int)blockIdx.z;

    const unsigned short* Ab;
    const unsigned short* Bb;
    unsigned short* Cp;
    int ldc, colbase;
    if (y < 4) {
        Ab = ckvq;
        Bb = ukvb + (long long)n * (256 * 512) + (long long)y * 64 * 512;
        if (y < 2) { Cp = khb + (long long)n * T * QK; ldc = QK; colbase = y * 64; }
        else       { Cp = vbh + (long long)n * T * DH; ldc = DH; colbase = (y - 2) * 64; }
    } else {
        Ab = ckvq + DC;
        Bb = wqall + (long long)n * (192 * 512) + (long long)(y - 4) * 64 * 512;
        Cp = qhb + (long long)n * T * QK; ldc = QK; colbase = (y - 4) * 64;
    }

    f32x4 acc[2][2];
#pragma unroll
    for (int i = 0; i < 2; ++i)
#pragma unroll
        for (int j = 0; j < 2; ++j) acc[i][j] = (f32x4){0.f, 0.f, 0.f, 0.f};

    auto STAGE = [&](int buf, int k0) {
        async16(&Ab[(long long)(m0 + (tid >> 2)) * 1024 + k0 + (((tid & 3) ^ ((tid >> 3) & 3)) * 8)],
                &As[buf][wave * 512]);
        async16(&Bb[(long long)(tid >> 2) * 512 + k0 + (((tid & 3) ^ ((tid >> 3) & 3)) * 8)],
                &Bs[buf][wave * 512]);
    };

    STAGE(0, 0);
    __syncthreads();
    int cur = 0;
    for (int k0 = 0; k0 < DC; k0 += 32) {
        if (k0 + 32 < DC) STAGE(cur ^ 1, k0 + 32);
        short8 af[2], bfr[2];
#pragma unroll
        for (int i = 0; i < 2; ++i) {
            int row = wm + i * 16 + c;
            af[i] = *(const short8*)&As[cur][row * 32 + (q ^ ((row >> 1) & 3)) * 8];
        }
#pragma unroll
        for (int j = 0; j < 2; ++j) {
            int row = wn + j * 16 + c;
            bfr[j] = *(const short8*)&Bs[cur][row * 32 + (q ^ ((row >> 1) & 3)) * 8];
        }
#pragma unroll
        for (int i = 0; i < 2; ++i)
#pragma unroll
            for (int j = 0; j < 2; ++j)
                acc[i][j] = MFMA16(af[i], bfr[j], acc[i][j]);
        __syncthreads();
        cur ^= 1;
    }
#pragma unroll
    for (int i = 0; i < 2; ++i)
#pragma unroll
        for (int j = 0; j < 2; ++j) {
            int rbase = m0 + wm + i * 16 + q * 4;
            int col = colbase + wn + j * 16 + c;
#pragma unroll
            for (int rr = 0; rr < 4; ++rr)
                Cp[(long long)(rbase + rr) * ldc + col] = f2b(acc[i][j][rr]);
        }
}

// ---------------- RoPE (merged q + k) ----------------
__global__ __launch_bounds__(256) void rope_qk(unsigned short* __restrict__ qh,
                                               const float* __restrict__ krtp,
                                               unsigned short* __restrict__ kh,
                                               const float* __restrict__ fr)
{
    int idx = (int)blockIdx.x * 256 + (int)threadIdx.x;
    if (idx < NH * T * 32) {               // ---- rope_q ----
        int j = idx & 31;
        int t = (idx >> 5) & (T - 1);
        int n = idx >> 16;
        float sn, cs;
        sincosf(fr[t * 32 + j], &sn, &cs);
        long long base = ((long long)(n * T + t)) * QK + 128 + j;
        float x0 = b2f(qh[base]);
        float x1 = b2f(qh[base + 32]);
        qh[base]      = f2b(x0 * cs - x1 * sn);
        qh[base + 32] = f2b(x0 * sn + x1 * cs);
    } else {                               // ---- rope_k ----
        idx -= NH * T * 32;
        int j = idx & 31;
        int t = idx >> 5;
        float sn, cs;
        sincosf(fr[t * 32 + j], &sn, &cs);
        float x0 = 0.f, x1 = 0.f;
#pragma unroll
        for (int pth = 0; pth < 4; ++pth) {
            x0 += krtp[pth * (T * 64) + t * 64 + j];
            x1 += krtp[pth * (T * 64) + t * 64 + 32 + j];
        }
        unsigned short y0 = f2b((x0 * cs - x1 * sn) * (1.0f / 16.0f));
        unsigned short y1 = f2b((x0 * sn + x1 * cs) * (1.0f / 16.0f));
#pragma unroll
        for (int n = 0; n < NH; ++n) {
            long long base = ((long long)(n * T + t)) * QK + 128 + j;
            kh[base]      = y0;
            kh[base + 32] = y1;
        }
    }
}

// vbh[n][t][e] -> vt[n][e][t] scaled by 1/z_t
__global__ __launch_bounds__(256) void vtrans(const unsigned short* __restrict__ vbh,
                                              const float* __restrict__ zrow,
                                              unsigned short* __restrict__ vt)
{
    __shared__ unsigned short ts[32][33];
    __shared__ float zi[32];
    int t0 = (int)blockIdx.x * 32, e0 = (int)blockIdx.y * 32, n = (int)blockIdx.z;
    int tid = (int)threadIdx.x;
    if (tid < 32) zi[tid] = 1.0f / zrow[n * T + t0 + tid];
    int r = tid >> 3, cq = (tid & 7) * 4;
    const unsigned short* src = vbh + ((long long)(n * T + t0 + r)) * DH + e0 + cq;
#pragma unroll
    for (int i = 0; i < 4; ++i) ts[r][cq + i] = src[i];
    __syncthreads();
    unsigned short* dst = vt + ((long long)(n * DH + e0 + r)) * T + t0 + cq;
#pragma unroll
    for (int i = 0; i < 4; ++i) dst[i] = f2b(b2f(ts[cq + i][r]) * zi[cq + i]);
}

// ---------------- Pass A: z_t AND P^T store (single QK^T) ----------------
// v10/v13 implementation (empirical local optimum: 45.4us, VGPR 92). Operand-
// swapped MFMA: D row = l (A = K rows), D col = t (B = Q rows). P^T =
// bf16_trunc(exp2(s*scl)) stored triangle-packed per head; z via atomics.
// 1D grid 2048, XCD-swizzled, longest-first (tbi=31 first), 4 l-chunks.
__global__ __launch_bounds__(256) void row_stats_p(const unsigned short* __restrict__ qh,
                                                   const unsigned short* __restrict__ kh,
                                                   float* __restrict__ zrow,
                                                   unsigned short* __restrict__ Pbuf)
{
    int id = (int)blockIdx.x;
    int n = (id & 7) * 2 + ((id >> 3) & 1);
    int rest = id >> 4;                      // 0..127
    int tbi = 31 - (rest & 31);              // longest (tbi=31) first
    int chunk = rest >> 5;                   // 0..3
    int tid = (int)threadIdx.x, wave = tid >> 6, lane = tid & 63;
    int q = lane >> 4, c = lane & 15;
    int tw = tbi * 64 + wave * 16;

    __shared__ unsigned short Ks[64 * 200];

    // Q fragments for the wave's 16 t-rows (B operand)
    const unsigned short* qp = qh + ((long long)(n * T + tw + c)) * QK;
    short8 qf[6];
#pragma unroll
    for (int f = 0; f < 6; ++f) qf[f] = *(const short8*)(qp + f * 32 + q * 8);

    float z = 0.f;                           // z partial for t = tw + c
    const unsigned short* kbase = kh + (long long)n * T * QK;
    unsigned short* Ph = Pbuf + (long long)n * PH;

    short8 kreg[6];
    int lt = chunk;
    if (lt <= tbi) {
        const unsigned short* kp = kbase + (long long)lt * 64 * QK;
#pragma unroll
        for (int i = 0; i < 6; ++i) {
            int ch = tid + i * 256;
            int r = ch / 24, cc = ch - r * 24;
            kreg[i] = *(const short8*)(kp + r * QK + cc * 8);
        }
    }
    for (; lt <= tbi; lt += 4) {
        __syncthreads();
#pragma unroll
        for (int i = 0; i < 6; ++i) {
            int ch = tid + i * 256;
            int r = ch / 24, cc = ch - r * 24;
            *(short8*)&Ks[r * 200 + cc * 8] = kreg[i];
        }
        __syncthreads();
        if (lt + 4 <= tbi) {
            const unsigned short* kp = kbase + (long long)(lt + 4) * 64 * QK;
#pragma unroll
            for (int i = 0; i < 6; ++i) {
                int ch = tid + i * 256;
                int r = ch / 24, cc = ch - r * 24;
                kreg[i] = *(const short8*)(kp + r * QK + cc * 8);
            }
        }
        f32x4 d[4];
#pragma unroll
        for (int ls = 0; ls < 4; ++ls) d[ls] = (f32x4){0.f, 0.f, 0.f, 0.f};
        __builtin_amdgcn_s_setprio(1);
#pragma unroll
        for (int f = 0; f < 6; ++f)
#pragma unroll
            for (int ls = 0; ls < 4; ++ls) {
                short8 ka = *(const short8*)&Ks[(ls * 16 + c) * 200 + f * 32 + q * 8];
                d[ls] = MFMA16(ka, qf[f], d[ls]);
            }
        __builtin_amdgcn_s_setprio(0);
        // P^T tile base: tile lt, row (l-64lt) = ls*16+q*4+r, col (t-64lt)
        int L = T - lt * 64;                 // packed row length for tile lt
        unsigned short* pb = Ph + (long long)2048 * lt * (65 - lt)
                             + (long long)(q * 4) * L + (tbi - lt) * 64 + wave * 16 + c;
        if (lt == tbi) {                     // diagonal tile: mask l > t, store zeros
            int tl = wave * 16 + c;
#pragma unroll
            for (int ls = 0; ls < 4; ++ls)
#pragma unroll
                for (int r = 0; r < 4; ++r) {
                    float pe = exp2f(d[ls][r] * SCL2E);
                    bool ok = (ls * 16 + q * 4 + r) <= tl;
                    z += ok ? pe : 0.f;
                    pb[(ls * 16 + r) * L] = ok ? f2bt(pe) : (unsigned short)0;
                }
        } else {
#pragma unroll
            for (int ls = 0; ls < 4; ++ls)
#pragma unroll
                for (int r = 0; r < 4; ++r) {
                    float pe = exp2f(d[ls][r] * SCL2E);
                    z += pe;
                    pb[(ls * 16 + r) * L] = f2bt(pe);
                }
        }
    }
    // reduce z over the q dimension (lanes c, c+16, c+32, c+48 share t = tw+c)
    z += __shfl_xor(z, 16);
    z += __shfl_xor(z, 32);
    if (q == 0) atomicAdd(&zrow[n * T + tw + c], z);
}

// ---------------- Pass B: out[l][n*128+e] = sum_t P^T[l][t] * V'[e][t] ----------------
// NT GEMM on triangle-packed P^T (A) and vt (B), dbuf staging, pair-balanced:
// block = (head, pair pr, chunk of 2) processes l-tiles {pr, 31-pr} -> 33 t-tiles
// per pair. 2 chunks -> 2 bf16 partials. 512 uniform blocks = 2/CU.
__global__ __launch_bounds__(256) void pv_gemm(const unsigned short* __restrict__ Pbuf,
                                               const unsigned short* __restrict__ vt,
                                               unsigned short* __restrict__ p0,
                                               unsigned short* __restrict__ p1)
{
    __shared__ unsigned short As[2][64 * 32];
    __shared__ unsigned short Bs[2][128 * 32];
    int id = (int)blockIdx.x;
    int n = (id & 7) * 2 + ((id >> 3) & 1);
    int rest = id >> 4;                      // 0..31
    int pr = rest & 15;                      // pair index 0..15
    int chunk = (rest >> 4) & 1;             // 0..1
    const int tid = (int)threadIdx.x, wave = tid >> 6, lane = tid & 63;
    const int q = lane >> 4, c = lane & 15;
    const int wm = (wave >> 1) * 32, wn = (wave & 1) * 64;
    unsigned short* op = chunk ? p1 : p0;

#pragma unroll
    for (int ph = 0; ph < 2; ++ph) {
        int j = ph ? (31 - pr) : pr;
        int m0 = j * 64;
        int L = T - m0;                      // packed lda and K extent
        int ntile = 32 - j;
        const unsigned short* A = Pbuf + (long long)n * PH + (long long)2048 * j * (65 - j);
        const unsigned short* B = vt + (long long)n * DH * T + m0;

        f32x4 acc[2][4];
#pragma unroll
        for (int i = 0; i < 2; ++i)
#pragma unroll
            for (int jj = 0; jj < 4; ++jj) acc[i][jj] = (f32x4){0.f, 0.f, 0.f, 0.f};

        int tcnt = (chunk < ntile) ? (((ntile - 1 - chunk) >> 1) + 1) : 0;
        int nsteps = tcnt * 2;

        auto STAGE = [&](int buf, int k0) {
            async16(&A[(long long)(tid >> 2) * L + k0 + (((tid & 3) ^ ((tid >> 3) & 3)) * 8)],
                    &As[buf][wave * 512]);
#pragma unroll
            for (int i = 0; i < 2; ++i) {
                int ch = tid + i * 256;
                async16(&B[(long long)(ch >> 2) * T + k0 + (((ch & 3) ^ ((ch >> 3) & 3)) * 8)],
                        &Bs[buf][(i * 256 + wave * 64) * 8]);
            }
        };
        auto K0 = [&](int s) { return (chunk + ((s >> 1) << 1)) * 64 + (s & 1) * 32; };

        if (nsteps > 0) STAGE(0, K0(0));
        __syncthreads();
        int cur = 0;
        for (int s = 0; s < nsteps; ++s) {
            if (s + 1 < nsteps) STAGE(cur ^ 1, K0(s + 1));
            short8 af[2], bfr[4];
#pragma unroll
            for (int i = 0; i < 2; ++i) {
                int row = wm + i * 16 + c;
                af[i] = *(const short8*)&As[cur][row * 32 + (q ^ ((row >> 1) & 3)) * 8];
            }
#pragma unroll
            for (int jj = 0; jj < 4; ++jj) {
                int row = wn + jj * 16 + c;
                bfr[jj] = *(const short8*)&Bs[cur][row * 32 + (q ^ ((row >> 1) & 3)) * 8];
            }
#pragma unroll
            for (int i = 0; i < 2; ++i)
#pragma unroll
                for (int jj = 0; jj < 4; ++jj)
                    acc[i][jj] = MFMA16(af[i], bfr[jj], acc[i][jj]);
            __syncthreads();
            cur ^= 1;
        }
        // always write (zeros when this chunk has no tiles) — partials are summed
#pragma unroll
        for (int i = 0; i < 2; ++i)
#pragma unroll
            for (int jj = 0; jj < 4; ++jj) {
                int rbase = m0 + wm + i * 16 + q * 4;
                int col = n * 128 + wn + jj * 16 + c;
#pragma unroll
                for (int rr = 0; rr < 4; ++rr)
                    op[(long long)(rbase + rr) * D + col] = f2b(acc[i][jj][rr]);
            }
        __syncthreads();                   // LDS reuse across phases
    }
}

// Merged epilogue prep: blocks [0,D) -> wo_permute; blocks [D, D + T*D/2048) -> sum_cast2.
// wob[d][n*128 + e] = bf16(wo[d][e*16 + n]); attn2 = bf16(p0 + p1) (o may alias a).
__global__ __launch_bounds__(256) void epilogue_prep(const float* __restrict__ wo,
                                                     unsigned short* __restrict__ wob,
                                                     const unsigned short* a,
                                                     const unsigned short* b,
                                                     unsigned short* o)
{
    __shared__ float row[2048];
    int bid = (int)blockIdx.x;
    if (bid < D) {                         // ---- wo_permute ----
        const float* src = wo + (long long)bid * 2048;
#pragma unroll
        for (int i = 0; i < 8; ++i) row[threadIdx.x + i * 256] = src[threadIdx.x + i * 256];
        __syncthreads();
        unsigned short* dst = wob + (long long)bid * 2048;
#pragma unroll
        for (int i = 0; i < 8; ++i) {
            int j = threadIdx.x + i * 256;
            int n = j >> 7, e = j & 127;
            dst[j] = f2b(row[e * 16 + n]);
        }
    } else {                               // ---- sum_cast2 ----
        long long i = ((long long)(bid - D) * 256 + threadIdx.x) * 8;
        short8 va = *(const short8*)(a + i);
        short8 vb = *(const short8*)(b + i);
        short8 vo;
#pragma unroll
        for (int j = 0; j < 8; ++j)
            vo[j] = (short)f2b(b2f((unsigned short)va[j]) + b2f((unsigned short)vb[j]));
        *(short8*)(o + i) = vo;
    }
}

} // namespace

extern "C" void kernel_launch(void* const* d_in, const int* in_sizes, int n_in,
                              void* d_out, int out_size, void* d_ws, size_t ws_size,
                              hipStream_t stream)
{
    (void)in_sizes; (void)n_in; (void)out_size; (void)ws_size;
    const float* h    = (const float*)d_in[0];
    const float* fr   = (const float*)d_in[1];
    const float* wdkv = (const float*)d_in[3];
    const float* wuk  = (const float*)d_in[4];
    const float* wuv  = (const float*)d_in[5];
    const float* wdq  = (const float*)d_in[6];
    const float* wuq  = (const float*)d_in[7];
    const float* wqr  = (const float*)d_in[8];
    const float* wkr  = (const float*)d_in[9];
    const float* wo   = (const float*)d_in[10];
    float* out = (float*)d_out;

    char* p = (char*)d_ws;
    auto alloc = [&](long long bytes) { char* r = p; p += (bytes + 255) & ~255LL; return r; };
    // Persistent-through-attention buffers first:
    unsigned short* qhb   = (unsigned short*)alloc((long long)NH * T * QK * 2); // 12.6 MB
    unsigned short* khb   = (unsigned short*)alloc((long long)NH * T * QK * 2); // 12.6 MB
    unsigned short* vbh   = (unsigned short*)alloc((long long)NH * T * DH * 2); //  8.4 MB
    float*          zrow  = (float*)alloc((long long)NH * T * 4);
    unsigned short* vtb   = (unsigned short*)alloc((long long)NH * T * DH * 2); //  8.4 MB
    unsigned short* Pbuf  = (unsigned short*)alloc(PH * NH * 2);                // 69.2 MB
    // Early-phase buffers overlay the P region (all dead before row_stats_p):
    char* q = (char*)Pbuf;
    auto sub = [&](long long bytes) { char* r = q; q += (bytes + 255) & ~255LL; return r; };
    unsigned short* hb    = (unsigned short*)sub(SZ_H * 2);
    unsigned short* dkvb  = (unsigned short*)sub(SZ_DKV * 2);   // dqb must follow dkvb
    unsigned short* dqb   = (unsigned short*)sub(SZ_DQ * 2);    // contiguously (merged B)
    unsigned short* ukvb  = (unsigned short*)sub((SZ_UK + SZ_UV) * 2); // [n][256][512]
    unsigned short* wqall = (unsigned short*)sub((SZ_UQ + SZ_QR) * 2); // [n][192][512]
    unsigned short* krb   = (unsigned short*)sub(SZ_KR * 2);
    unsigned short* ckvq  = (unsigned short*)sub((long long)T * 1024 * 2); // [t][ckv|cq]
    float*          krt   = (float*)sub((long long)T * DRH * 4 * 4);      // 4 split-K partials
    // Late overlays:
    unsigned short* pvp0  = qhb;   // qhb dead after row_stats_p
    unsigned short* pvp1  = khb;   // khb dead after row_stats_p
    unsigned short* attn2 = pvp0;  // sum_cast2 in-place into partial 0
    unsigned short* wob   = vtb;   // vtb dead after pv_gemm

    cast_all<<<dim3((unsigned)(C8 / 1024)), 256, 0, stream>>>(
        h, wdkv, wuk, wuv, wdq, wuq, wqr, wkr, hb, dkvb, dqb, ukvb, wqall, krb, zrow);

    // FUSED down-proj + k_r down-proj: y<16 -> ckvq[t][0:1024] (K=2048);
    // y in [16,20) -> krt split-K slice z=y-16 (K=512, fp32 partials).
    gemm_bf16<64,64,32,32,true,true><<<dim3(T/64, 20, 1), 256, 0, stream>>>(
        hb, dkvb, ckvq, D, D, D, 1024, krt, krb);

    // FUSED k_c / v_c / q up-projections (A = ckvq), 3584 blocks = 14/CU.
    up_proj_fused<<<dim3(T/64, 7, NH), 256, 0, stream>>>(
        ckvq, ukvb, wqall, khb, vbh, qhb);

    rope_qk<<<dim3((NH * T * 32 + T * 32) / 256), 256, 0, stream>>>(qhb, krt, khb, fr);

    row_stats_p<<<dim3(2048), 256, 0, stream>>>(qhb, khb, zrow, Pbuf);
    vtrans<<<dim3(T/32, DH/32, NH), 256, 0, stream>>>(vbh, zrow, vtb);
    pv_gemm<<<dim3(512), 256, 0, stream>>>(Pbuf, vtb, pvp0, pvp1);

    epilogue_prep<<<dim3(D + T * D / 2048), 256, 0, stream>>>(wo, wob, pvp0, pvp1, attn2);

    gemm_bf16<64,128,32,64,false><<<dim3(T/64, 16, 1), 256, 0, stream>>>(
        attn2, wob, out, D, D, D, D, nullptr, nullptr);
}